// Round 7
// baseline (27.199 us; speedup 1.0000x reference)
//
#include <hip/hip_runtime.h>
#include <math.h>
#include <stdint.h>

#define Bsz 512
#define Nn 8192
#define Hh 5
#define Ss 10
#define KB 8            // batches per block
#define TILE 1024       // n per block
#define NT 256          // threads per block
#define TILES (Nn / TILE)

// LDS float layout (60 KB total, all regions WAVE-PRIVATE -> barrier-free):
//   [w*2560, w*2560+2560)   : wave w's region. Prologue: sW staging (2560 floats).
//                             Main loop: history double buffer (2 x 1280 floats).
//   [10240 + w*1280, +1280) : wave w's hw staging region.
#define LDS_FLOATS 15360

__device__ __forceinline__ float elu1(float v) {
    return v > 0.0f ? v : expm1f(v);
}

// One async global->LDS 16B/lane transfer: 64 lanes x 16 B = 1024 B = 256 floats.
// src is per-lane (pass base + lane*4 floats); dst is wave-uniform base.
__device__ __forceinline__ void gload16(const float* src, float* dst) {
    __builtin_amdgcn_global_load_lds(
        (const __attribute__((address_space(1))) uint32_t*)src,
        (__attribute__((address_space(3))) uint32_t*)dst, 16, 0, 0);
}

__global__ __launch_bounds__(NT, 2) void main_kernel(
    const float* __restrict__ x,         // [B,N]
    const float* __restrict__ history,   // [B,N,H]
    const float* __restrict__ state,     // [B,S]
    const float* __restrict__ hw,        // [N,H]
    const float* __restrict__ hb,        // [N]
    const float* __restrict__ sW,        // [N,S]
    const float* __restrict__ sb,        // [N]
    const float* __restrict__ ga,        // [N]
    const int*   __restrict__ sort_id,   // [B]
    const float* __restrict__ own_gain,  // [T]
    float* __restrict__ out)             // [B,N]
{
    __shared__ __align__(16) float lds[LDS_FLOATS];

    const int tid  = threadIdx.x;
    const int lane = tid & 63;
    const int wave = tid >> 6;
    const int tile  = blockIdx.x & (TILES - 1);
    const int chunk = blockIdx.x / TILES;
    const int n0 = tile * TILE;
    const int b0 = chunk * KB;
    const int nq = n0 + tid * 4;

    float* myreg = &lds[wave * 2560];          // sW staging, then hist dbuf
    float* myhw  = &lds[10240 + wave * 1280];  // hw staging

    // ---- per-n biases (dense, coalesced) ----
    float4 hbv = *reinterpret_cast<const float4*>(hb + nq);
    float4 sbv = *reinterpret_cast<const float4*>(sb + nq);
    float4 gav = *reinterpret_cast<const float4*>(ga + nq);

    // ---- batch gains, wave-parallel: 8 lane-groups x 8 lanes, taps j = r+8k ----
    float bgv[KB];
    {
        int grp = lane >> 3;
        int r   = lane & 7;
        int s   = sort_id[b0 + grp];
        int jmax = s < 100 ? s : 100;
        float acc = 0.0f;
        #pragma unroll
        for (int k = 0; k < 13; ++k) {
            int j = r + k * 8;
            if (j <= jmax) {
                float t = (float)j * (1.0f / 30.0f);
                acc = fmaf(expf(-0.5f * t * t), own_gain[s - j], acc);
            }
        }
        acc += __shfl_xor(acc, 1);
        acc += __shfl_xor(acc, 2);
        acc += __shfl_xor(acc, 4);
        #pragma unroll
        for (int g = 0; g < KB; ++g)
            bgv[g] = elu1(__shfl(acc, g * 8)) + 1.0f;
    }

    // ---- stage sW (10 loads) + hw (5 loads) into wave-private regions ----
    {
        const float* srcS = sW + (size_t)n0 * Ss + wave * 2560 + lane * 4;
        #pragma unroll
        for (int p = 0; p < 10; ++p) gload16(srcS + p * 256, myreg + p * 256);
        const float* srcA = hw + (size_t)n0 * Hh + wave * 1280 + lane * 4;
        #pragma unroll
        for (int p = 0; p < 5; ++p)  gload16(srcA + p * 256, myhw + p * 256);
    }
    asm volatile("s_waitcnt vmcnt(0)" ::: "memory");

    // ---- weights LDS -> registers (wave-private, no barrier needed) ----
    float wS[40], wA[20];
    #pragma unroll
    for (int i = 0; i < 10; ++i) {
        float4 t = *reinterpret_cast<float4*>(&myreg[lane * 40 + i * 4]);
        wS[i*4+0] = t.x; wS[i*4+1] = t.y; wS[i*4+2] = t.z; wS[i*4+3] = t.w;
    }
    #pragma unroll
    for (int i = 0; i < 5; ++i) {
        float4 t = *reinterpret_cast<float4*>(&myhw[lane * 20 + i * 4]);
        wA[i*4+0] = t.x; wA[i*4+1] = t.y; wA[i*4+2] = t.z; wA[i*4+3] = t.w;
    }
    asm volatile("" ::: "memory");   // weights consumed before region reuse below

    // ---- prologue prefetch: history[b0] -> buf0, x[b0] -> reg ----
    {
        const float* src = history + ((size_t)b0 * Nn + n0) * Hh + wave * 1280 + lane * 4;
        #pragma unroll
        for (int p = 0; p < 5; ++p) gload16(src + p * 256, myreg + p * 256);
    }
    float4 xv = *reinterpret_cast<const float4*>(x + (size_t)b0 * Nn + nq);

    #pragma unroll
    for (int kb = 0; kb < KB; ++kb) {
        const int b = b0 + kb;

        // own staged data landed (wave-private; no __syncthreads anywhere)
        asm volatile("s_waitcnt vmcnt(0)" ::: "memory");

        // prefetch next batch into the other half of this wave's region
        float4 xnext = xv;
        if (kb + 1 < KB) {
            const float* src = history + ((size_t)(b + 1) * Nn + n0) * Hh
                               + wave * 1280 + lane * 4;
            float* dst = myreg + ((kb + 1) & 1) * 1280;
            #pragma unroll
            for (int p = 0; p < 5; ++p) gload16(src + p * 256, dst + p * 256);
            xnext = *reinterpret_cast<const float4*>(x + (size_t)(b + 1) * Nn + nq);
        }

        // block-uniform state -> scalar loads
        float st[Ss];
        #pragma unroll
        for (int i = 0; i < Ss; ++i) st[i] = state[b * Ss + i];

        // history dot from this wave's current buffer
        const float* buf = myreg + (kb & 1) * 1280 + lane * 20;
        float hist[4] = {hbv.x, hbv.y, hbv.z, hbv.w};
        #pragma unroll
        for (int i = 0; i < 5; ++i) {
            float4 h = *reinterpret_cast<const float4*>(buf + i * 4);
            float hv4[4] = {h.x, h.y, h.z, h.w};
            #pragma unroll
            for (int j = 0; j < 4; ++j) {
                int f = i * 4 + j;                 // f = q*5 + h
                hist[f / Hh] = fmaf(hv4[j], wA[f], hist[f / Hh]);
            }
        }

        float sm[4] = {sbv.x, sbv.y, sbv.z, sbv.w};
        #pragma unroll
        for (int f = 0; f < 40; ++f)               // f = q*10 + s
            sm[f / Ss] = fmaf(st[f % Ss], wS[f], sm[f / Ss]);

        float xa[4]  = {xv.x, xv.y, xv.z, xv.w};
        float gaa[4] = {gav.x, gav.y, gav.z, gav.w};
        float res[4];
        #pragma unroll
        for (int q = 0; q < 4; ++q) {
            float v = xa[q] + hist[q] + elu1(sm[q]);
            res[q] = fmaf(gaa[q], bgv[kb], 1.0f) * (elu1(v) + 1.0f);
        }
        *reinterpret_cast<float4*>(out + (size_t)b * Nn + nq) =
            make_float4(res[0], res[1], res[2], res[3]);

        xv = xnext;
    }
}

extern "C" void kernel_launch(void* const* d_in, const int* in_sizes, int n_in,
                              void* d_out, int out_size, void* d_ws, size_t ws_size,
                              hipStream_t stream) {
    const float* x        = (const float*)d_in[0];
    const float* history  = (const float*)d_in[1];
    // d_in[2] = gain (unused)
    const float* state    = (const float*)d_in[3];
    const int*   sort_id  = (const int*)d_in[4];
    const float* hw       = (const float*)d_in[5];
    const float* hb       = (const float*)d_in[6];
    const float* sW       = (const float*)d_in[7];
    const float* sb       = (const float*)d_in[8];
    const float* own_gain = (const float*)d_in[9];
    const float* ga       = (const float*)d_in[10];
    float* out = (float*)d_out;

    const int nblocks = TILES * (Bsz / KB);   // 8 * 64 = 512 -> 2 blocks/CU exact
    main_kernel<<<nblocks, NT, 0, stream>>>(x, history, state, hw, hb, sW, sb,
                                            ga, sort_id, own_gain, out);
}

// Round 8
// 27.124 us; speedup vs baseline: 1.0028x; 1.0028x over previous
//
#include <hip/hip_runtime.h>
#include <math.h>
#include <stdint.h>

#define Bsz 512
#define Nn 8192
#define Hh 5
#define Ss 10
#define KB 8            // batches per block
#define TILE 1024       // n per block
#define NT 256          // threads per block
#define TILES (Nn / TILE)

// LDS float layout (60 KB total, all regions WAVE-PRIVATE -> barrier-free):
//   [w*2560, w*2560+2560)   : wave w's region. Prologue: sW staging (2560 floats).
//                             Main loop: history double buffer (2 x 1280 floats).
//   [10240 + w*1280, +1280) : wave w's hw staging region.
#define LDS_FLOATS 15360

__device__ __forceinline__ float elu1(float v) {
    return v > 0.0f ? v : expm1f(v);
}

// One async global->LDS 16B/lane transfer: 64 lanes x 16 B = 1024 B = 256 floats.
// src is per-lane (pass base + lane*4 floats); dst is wave-uniform base.
__device__ __forceinline__ void gload16(const float* src, float* dst) {
    __builtin_amdgcn_global_load_lds(
        (const __attribute__((address_space(1))) uint32_t*)src,
        (__attribute__((address_space(3))) uint32_t*)dst, 16, 0, 0);
}

__global__ __launch_bounds__(NT, 2) void main_kernel(
    const float* __restrict__ x,         // [B,N]
    const float* __restrict__ history,   // [B,N,H]
    const float* __restrict__ state,     // [B,S]
    const float* __restrict__ hw,        // [N,H]
    const float* __restrict__ hb,        // [N]
    const float* __restrict__ sW,        // [N,S]
    const float* __restrict__ sb,        // [N]
    const float* __restrict__ ga,        // [N]
    const int*   __restrict__ sort_id,   // [B]
    const float* __restrict__ own_gain,  // [T]
    float* __restrict__ out)             // [B,N]
{
    __shared__ __align__(16) float lds[LDS_FLOATS];

    const int tid  = threadIdx.x;
    const int lane = tid & 63;
    const int wave = tid >> 6;
    const int tile  = blockIdx.x & (TILES - 1);
    const int chunk = blockIdx.x / TILES;
    const int n0 = tile * TILE;
    const int b0 = chunk * KB;
    const int nq = n0 + tid * 4;

    float* myreg = &lds[wave * 2560];          // sW staging, then hist dbuf
    float* myhw  = &lds[10240 + wave * 1280];  // hw staging

    // ---- per-n biases (dense, coalesced) ----
    float4 hbv = *reinterpret_cast<const float4*>(hb + nq);
    float4 sbv = *reinterpret_cast<const float4*>(sb + nq);
    float4 gav = *reinterpret_cast<const float4*>(ga + nq);

    // ---- batch gains, wave-parallel: 8 lane-groups x 8 lanes, taps j = r+8k ----
    float bgv[KB];
    {
        int grp = lane >> 3;
        int r   = lane & 7;
        int s   = sort_id[b0 + grp];
        int jmax = s < 100 ? s : 100;
        float acc = 0.0f;
        #pragma unroll
        for (int k = 0; k < 13; ++k) {
            int j = r + k * 8;
            if (j <= jmax) {
                float t = (float)j * (1.0f / 30.0f);
                acc = fmaf(expf(-0.5f * t * t), own_gain[s - j], acc);
            }
        }
        acc += __shfl_xor(acc, 1);
        acc += __shfl_xor(acc, 2);
        acc += __shfl_xor(acc, 4);
        #pragma unroll
        for (int g = 0; g < KB; ++g)
            bgv[g] = elu1(__shfl(acc, g * 8)) + 1.0f;
    }

    // ---- stage sW (10 loads) + hw (5 loads) into wave-private regions ----
    {
        const float* srcS = sW + (size_t)n0 * Ss + wave * 2560 + lane * 4;
        #pragma unroll
        for (int p = 0; p < 10; ++p) gload16(srcS + p * 256, myreg + p * 256);
        const float* srcA = hw + (size_t)n0 * Hh + wave * 1280 + lane * 4;
        #pragma unroll
        for (int p = 0; p < 5; ++p)  gload16(srcA + p * 256, myhw + p * 256);
    }
    asm volatile("s_waitcnt vmcnt(0)" ::: "memory");

    // ---- weights LDS -> registers (wave-private, no barrier needed) ----
    float wS[40], wA[20];
    #pragma unroll
    for (int i = 0; i < 10; ++i) {
        float4 t = *reinterpret_cast<float4*>(&myreg[lane * 40 + i * 4]);
        wS[i*4+0] = t.x; wS[i*4+1] = t.y; wS[i*4+2] = t.z; wS[i*4+3] = t.w;
    }
    #pragma unroll
    for (int i = 0; i < 5; ++i) {
        float4 t = *reinterpret_cast<float4*>(&myhw[lane * 20 + i * 4]);
        wA[i*4+0] = t.x; wA[i*4+1] = t.y; wA[i*4+2] = t.z; wA[i*4+3] = t.w;
    }
    asm volatile("" ::: "memory");   // weights consumed before region reuse below

    // ---- prologue prefetch: history[b0] -> buf0, x[b0] -> reg ----
    {
        const float* src = history + ((size_t)b0 * Nn + n0) * Hh + wave * 1280 + lane * 4;
        #pragma unroll
        for (int p = 0; p < 5; ++p) gload16(src + p * 256, myreg + p * 256);
    }
    float4 xv = *reinterpret_cast<const float4*>(x + (size_t)b0 * Nn + nq);

    #pragma unroll
    for (int kb = 0; kb < KB; ++kb) {
        const int b = b0 + kb;

        // own staged data landed (wave-private; no __syncthreads anywhere)
        asm volatile("s_waitcnt vmcnt(0)" ::: "memory");

        // prefetch next batch into the other half of this wave's region
        float4 xnext = xv;
        if (kb + 1 < KB) {
            const float* src = history + ((size_t)(b + 1) * Nn + n0) * Hh
                               + wave * 1280 + lane * 4;
            float* dst = myreg + ((kb + 1) & 1) * 1280;
            #pragma unroll
            for (int p = 0; p < 5; ++p) gload16(src + p * 256, dst + p * 256);
            xnext = *reinterpret_cast<const float4*>(x + (size_t)(b + 1) * Nn + nq);
        }

        // block-uniform state -> scalar loads
        float st[Ss];
        #pragma unroll
        for (int i = 0; i < Ss; ++i) st[i] = state[b * Ss + i];

        // history dot from this wave's current buffer
        const float* buf = myreg + (kb & 1) * 1280 + lane * 20;
        float hist[4] = {hbv.x, hbv.y, hbv.z, hbv.w};
        #pragma unroll
        for (int i = 0; i < 5; ++i) {
            float4 h = *reinterpret_cast<const float4*>(buf + i * 4);
            float hv4[4] = {h.x, h.y, h.z, h.w};
            #pragma unroll
            for (int j = 0; j < 4; ++j) {
                int f = i * 4 + j;                 // f = q*5 + h
                hist[f / Hh] = fmaf(hv4[j], wA[f], hist[f / Hh]);
            }
        }

        float sm[4] = {sbv.x, sbv.y, sbv.z, sbv.w};
        #pragma unroll
        for (int f = 0; f < 40; ++f)               // f = q*10 + s
            sm[f / Ss] = fmaf(st[f % Ss], wS[f], sm[f / Ss]);

        float xa[4]  = {xv.x, xv.y, xv.z, xv.w};
        float gaa[4] = {gav.x, gav.y, gav.z, gav.w};
        float res[4];
        #pragma unroll
        for (int q = 0; q < 4; ++q) {
            float v = xa[q] + hist[q] + elu1(sm[q]);
            res[q] = fmaf(gaa[q], bgv[kb], 1.0f) * (elu1(v) + 1.0f);
        }
        *reinterpret_cast<float4*>(out + (size_t)b * Nn + nq) =
            make_float4(res[0], res[1], res[2], res[3]);

        xv = xnext;
    }
}

extern "C" void kernel_launch(void* const* d_in, const int* in_sizes, int n_in,
                              void* d_out, int out_size, void* d_ws, size_t ws_size,
                              hipStream_t stream) {
    const float* x        = (const float*)d_in[0];
    const float* history  = (const float*)d_in[1];
    // d_in[2] = gain (unused)
    const float* state    = (const float*)d_in[3];
    const int*   sort_id  = (const int*)d_in[4];
    const float* hw       = (const float*)d_in[5];
    const float* hb       = (const float*)d_in[6];
    const float* sW       = (const float*)d_in[7];
    const float* sb       = (const float*)d_in[8];
    const float* own_gain = (const float*)d_in[9];
    const float* ga       = (const float*)d_in[10];
    float* out = (float*)d_out;

    const int nblocks = TILES * (Bsz / KB);   // 8 * 64 = 512 -> 2 blocks/CU exact
    main_kernel<<<nblocks, NT, 0, stream>>>(x, history, state, hw, hb, sW, sb,
                                            ga, sort_id, own_gain, out);
}

// Round 9
// 25.684 us; speedup vs baseline: 1.0590x; 1.0560x over previous
//
#include <hip/hip_runtime.h>
#include <math.h>
#include <stdint.h>

#define Bsz 512
#define Nn 8192
#define Hh 5
#define Ss 10
#define KB 4            // batches per block
#define TILE 1024       // n per block
#define NT 256          // threads per block
#define TILES (Nn / TILE)

// LDS: per-wave double buffer 2x1280 floats, 4 waves -> 10240 floats = 40 KB.
// 4 blocks/CU x 40 KB = 160 KB exactly. All regions wave-private -> no barriers.
// Prologue reuses the same region for sW (full 2560) then hw (first 1280) staging.
#define LDS_FLOATS 10240

__device__ __forceinline__ float elu1(float v) {
    // |err| ~1e-7 vs expm1f; threshold is 0.4675 -> free accuracy slack.
    return v > 0.0f ? v : __expf(v) - 1.0f;
}

// One async global->LDS transfer: 64 lanes x 16 B = 1024 B = 256 floats.
// src per-lane (base + lane*4 floats); dst wave-uniform base (HW rule).
__device__ __forceinline__ void gload16(const float* src, float* dst) {
    __builtin_amdgcn_global_load_lds(
        (const __attribute__((address_space(1))) uint32_t*)src,
        (__attribute__((address_space(3))) uint32_t*)dst, 16, 0, 0);
}

__global__ __launch_bounds__(NT, 4) void main_kernel(
    const float* __restrict__ x,         // [B,N]
    const float* __restrict__ history,   // [B,N,H]
    const float* __restrict__ state,     // [B,S]
    const float* __restrict__ hw,        // [N,H]
    const float* __restrict__ hb,        // [N]
    const float* __restrict__ sW,        // [N,S]
    const float* __restrict__ sb,        // [N]
    const float* __restrict__ ga,        // [N]
    const int*   __restrict__ sort_id,   // [B]
    const float* __restrict__ own_gain,  // [T]
    float* __restrict__ out)             // [B,N]
{
    __shared__ __align__(16) float lds[LDS_FLOATS];

    const int tid  = threadIdx.x;
    const int lane = tid & 63;
    const int wave = tid >> 6;
    const int tile  = blockIdx.x & (TILES - 1);   // == XCD id under %8 round-robin
    const int chunk = blockIdx.x / TILES;
    const int n0 = tile * TILE;
    const int b0 = chunk * KB;
    const int nq = n0 + tid * 4;

    float* myreg = &lds[wave * 2560];

    // ---- per-n biases (dense, coalesced; consumed in the loop) ----
    float4 hbv = *reinterpret_cast<const float4*>(hb + nq);
    float4 sbv = *reinterpret_cast<const float4*>(sb + nq);
    float4 gav = *reinterpret_cast<const float4*>(ga + nq);

    // ---- batch gains, wave-parallel: 4 groups x 16 lanes, taps j = r+16k ----
    float bgv[KB];
    {
        int grp = lane >> 4;
        int r   = lane & 15;
        int s   = sort_id[b0 + grp];
        int jmax = s < 100 ? s : 100;
        float acc = 0.0f;
        #pragma unroll
        for (int k = 0; k < 7; ++k) {
            int j = r + k * 16;
            if (j <= jmax) {
                float t = (float)j * (1.0f / 30.0f);
                acc = fmaf(__expf(-0.5f * t * t), own_gain[s - j], acc);
            }
        }
        acc += __shfl_xor(acc, 1);
        acc += __shfl_xor(acc, 2);
        acc += __shfl_xor(acc, 4);
        acc += __shfl_xor(acc, 8);
        #pragma unroll
        for (int g = 0; g < KB; ++g)
            bgv[g] = elu1(__shfl(acc, g * 16)) + 1.0f;
    }

    // ---- phase A: sW tile -> LDS (wave-private 2560 floats) -> registers ----
    {
        const float* srcS = sW + (size_t)n0 * Ss + wave * 2560 + lane * 4;
        #pragma unroll
        for (int p = 0; p < 10; ++p) gload16(srcS + p * 256, myreg + p * 256);
    }
    asm volatile("s_waitcnt vmcnt(0)" ::: "memory");
    float wS[40];
    #pragma unroll
    for (int i = 0; i < 10; ++i) {
        float4 t = *reinterpret_cast<float4*>(&myreg[lane * 40 + i * 4]);
        wS[i*4+0] = t.x; wS[i*4+1] = t.y; wS[i*4+2] = t.z; wS[i*4+3] = t.w;
    }
    asm volatile("s_waitcnt lgkmcnt(0)" ::: "memory");   // reads done before overwrite

    // ---- phase B: hw tile -> LDS (first 1280 floats) -> registers ----
    {
        const float* srcA = hw + (size_t)n0 * Hh + wave * 1280 + lane * 4;
        #pragma unroll
        for (int p = 0; p < 5; ++p) gload16(srcA + p * 256, myreg + p * 256);
    }
    asm volatile("s_waitcnt vmcnt(0)" ::: "memory");
    float wA[20];
    #pragma unroll
    for (int i = 0; i < 5; ++i) {
        float4 t = *reinterpret_cast<float4*>(&myreg[lane * 20 + i * 4]);
        wA[i*4+0] = t.x; wA[i*4+1] = t.y; wA[i*4+2] = t.z; wA[i*4+3] = t.w;
    }
    asm volatile("s_waitcnt lgkmcnt(0)" ::: "memory");   // reads done before overwrite

    // ---- phase C: prologue prefetch: hist[b0] -> buf0 [5g], then x [1] ----
    {
        const float* h0 = history + ((size_t)b0 * Nn + n0) * Hh + wave * 1280 + lane * 4;
        #pragma unroll
        for (int p = 0; p < 5; ++p) gload16(h0 + p * 256, myreg + p * 256);
    }
    asm volatile("" ::: "memory");                       // pin: gloads before x-load
    float4 xv = *reinterpret_cast<const float4*>(x + (size_t)b0 * Nn + nq);
    asm volatile("" ::: "memory");

    #pragma unroll
    for (int kb = 0; kb < KB; ++kb) {
        const int b = b0 + kb;

        // Counted wait: the 5 hist gloads for THIS buffer are the oldest
        // outstanding ops; leave the newest (x-load [+ out-store]) in flight.
        if (kb == 0) asm volatile("s_waitcnt vmcnt(1)" ::: "memory");
        else         asm volatile("s_waitcnt vmcnt(2)" ::: "memory");

        // state: block-uniform (issued BEFORE next prefetch so it can't sit
        // between the gloads and the counted wait's accounting)
        float st[Ss];
        #pragma unroll
        for (int i = 0; i < Ss; ++i) st[i] = state[b * Ss + i];
        asm volatile("" ::: "memory");

        // prefetch next batch: exactly [5 gloads, x-load], in this order
        float4 xnext = xv;
        if (kb + 1 < KB) {
            const float* hn = history + ((size_t)(b + 1) * Nn + n0) * Hh
                              + wave * 1280 + lane * 4;
            float* dst = myreg + ((kb + 1) & 1) * 1280;
            #pragma unroll
            for (int p = 0; p < 5; ++p) gload16(hn + p * 256, dst + p * 256);
            asm volatile("" ::: "memory");
            xnext = *reinterpret_cast<const float4*>(x + (size_t)(b + 1) * Nn + nq);
        }
        asm volatile("" ::: "memory");

        // history dot from this wave's current buffer
        const float* buf = myreg + (kb & 1) * 1280 + lane * 20;
        float hist[4] = {hbv.x, hbv.y, hbv.z, hbv.w};
        #pragma unroll
        for (int i = 0; i < 5; ++i) {
            float4 h = *reinterpret_cast<const float4*>(buf + i * 4);
            float hv4[4] = {h.x, h.y, h.z, h.w};
            #pragma unroll
            for (int j = 0; j < 4; ++j) {
                int f = i * 4 + j;                 // f = q*5 + h
                hist[f / Hh] = fmaf(hv4[j], wA[f], hist[f / Hh]);
            }
        }

        float sm[4] = {sbv.x, sbv.y, sbv.z, sbv.w};
        #pragma unroll
        for (int f = 0; f < 40; ++f)               // f = q*10 + s
            sm[f / Ss] = fmaf(st[f % Ss], wS[f], sm[f / Ss]);

        float xa[4]  = {xv.x, xv.y, xv.z, xv.w};
        float gaa[4] = {gav.x, gav.y, gav.z, gav.w};
        float res[4];
        #pragma unroll
        for (int q = 0; q < 4; ++q) {
            float v = xa[q] + hist[q] + elu1(sm[q]);
            res[q] = fmaf(gaa[q], bgv[kb], 1.0f) * (elu1(v) + 1.0f);
        }
        *reinterpret_cast<float4*>(out + (size_t)b * Nn + nq) =
            make_float4(res[0], res[1], res[2], res[3]);

        xv = xnext;
    }
}

extern "C" void kernel_launch(void* const* d_in, const int* in_sizes, int n_in,
                              void* d_out, int out_size, void* d_ws, size_t ws_size,
                              hipStream_t stream) {
    const float* x        = (const float*)d_in[0];
    const float* history  = (const float*)d_in[1];
    // d_in[2] = gain (unused)
    const float* state    = (const float*)d_in[3];
    const int*   sort_id  = (const int*)d_in[4];
    const float* hw       = (const float*)d_in[5];
    const float* hb       = (const float*)d_in[6];
    const float* sW       = (const float*)d_in[7];
    const float* sb       = (const float*)d_in[8];
    const float* own_gain = (const float*)d_in[9];
    const float* ga       = (const float*)d_in[10];
    float* out = (float*)d_out;

    const int nblocks = TILES * (Bsz / KB);   // 8 * 128 = 1024 -> 4 blocks/CU
    main_kernel<<<nblocks, NT, 0, stream>>>(x, history, state, hw, hb, sW, sb,
                                            ga, sort_id, own_gain, out);
}

// Round 10
// 25.591 us; speedup vs baseline: 1.0629x; 1.0037x over previous
//
#include <hip/hip_runtime.h>
#include <stdint.h>

#define Bsz 512
#define Nn  8192
#define Hh  5
#define Ss  10
#define KB  8            // batches per block
#define TILE 512         // n per block
#define NT  256          // threads per block
#define TILES (Nn / TILE)   // 16

// Per-wave LDS region (floats): [0,1280) sW-stage (buf1 overlays [0,640))
//                               [1280,1920) hw-stage (= buf2 after prologue)
//                               [1920,2560) buf0
// buf(k) = k%3==0 ? buf0 : k%3==1 ? sW[0:640) : hw-region.  All wave-private.
#define WREG 2560
#define LDS_FLOATS (4 * WREG)   // 40 KB -> 4 blocks/CU exactly

#define FENCE() asm volatile("" ::: "memory")
#define LGKM0() asm volatile("s_waitcnt lgkmcnt(0)" ::: "memory")

__device__ __forceinline__ float elu1(float v) {
    return v > 0.0f ? v : __expf(v) - 1.0f;
}

__device__ __forceinline__ void gload16(const float* src, float* dst) {
    __builtin_amdgcn_global_load_lds(
        (const __attribute__((address_space(1))) uint32_t*)src,
        (__attribute__((address_space(3))) uint32_t*)dst, 16, 0, 0);
}
__device__ __forceinline__ void gload4(const float* src, float* dst) {
    __builtin_amdgcn_global_load_lds(
        (const __attribute__((address_space(1))) uint32_t*)src,
        (__attribute__((address_space(3))) uint32_t*)dst, 4, 0, 0);
}

// Stage 640 consecutive floats (2560 B) into a wave-private region: 2xg16 + 2xg4.
__device__ __forceinline__ void stage640(const float* src, float* dst, int L) {
    gload16(src + L * 4,       dst);
    gload16(src + 256 + L * 4, dst + 256);
    gload4 (src + 512 + L,     dst + 512);
    gload4 (src + 576 + L,     dst + 576);
}

__global__ __launch_bounds__(NT, 4) void main_kernel(
    const float* __restrict__ x,         // [B,N]
    const float* __restrict__ history,   // [B,N,H]
    const float* __restrict__ state,     // [B,S]
    const float* __restrict__ hw,        // [N,H]
    const float* __restrict__ hb,        // [N]
    const float* __restrict__ sW,        // [N,S]
    const float* __restrict__ sb,        // [N]
    const float* __restrict__ ga,        // [N]
    const int*   __restrict__ sort_id,   // [B]
    const float* __restrict__ own_gain,  // [T]
    float* __restrict__ out)             // [B,N]
{
    __shared__ __align__(16) float lds[LDS_FLOATS];

    const int tid = threadIdx.x;
    const int L   = tid & 63;
    const int w   = tid >> 6;
    const int tile  = blockIdx.x & (TILES - 1);
    const int chunk = blockIdx.x / TILES;
    const int n0 = tile * TILE;
    const int b0 = chunk * KB;
    // split-half ownership inside the wave's 128-n span -> 2-way-free LDS reads
    const int nA = n0 + 128 * w + L;
    const int nB = nA + 64;
    const int nwave = n0 + 128 * w;          // wave's first n

    float* WB  = &lds[w * WREG];
    float* RsW = WB;            // sW stage; [0,640) becomes buf1
    float* Rhw = WB + 1280;     // hw stage; becomes buf2
    float* Rb0 = WB + 1920;     // buf0

    // ---- gains (all vm loads here retire before the counted stream) ----
    float bg[KB];
    {
        int grp = L >> 3;                    // 8 groups x 8 lanes
        int r   = L & 7;
        int s   = sort_id[b0 + grp];
        int jmax = s < 100 ? s : 100;
        float acc = 0.0f;
        #pragma unroll
        for (int k = 0; k < 13; ++k) {
            int j = r + k * 8;
            if (j <= jmax) {
                float t = (float)j * (1.0f / 30.0f);
                acc = fmaf(__expf(-0.5f * t * t), own_gain[s - j], acc);
            }
        }
        acc += __shfl_xor(acc, 1);
        acc += __shfl_xor(acc, 2);
        acc += __shfl_xor(acc, 4);
        #pragma unroll
        for (int g = 0; g < KB; ++g)
            bg[g] = elu1(__shfl(acc, g * 8)) + 1.0f;
    }
    // biases (older than the counted stream -> drained first, counts stay valid)
    float hbA = hb[nA], hbB = hb[nB];
    float sbA = sb[nA], sbB = sb[nB];
    float gaA = ga[nA], gaB = ga[nB];
    FENCE();

    // ---- counted staging stream: [sW 5][hw 4][h0 4][x0 2] ----
    {
        const float* s0 = sW + (size_t)nwave * Ss;      // 1280 floats
        gload16(s0 + L * 4,        RsW);
        gload16(s0 + 256  + L * 4, RsW + 256);
        gload16(s0 + 512  + L * 4, RsW + 512);
        gload16(s0 + 768  + L * 4, RsW + 768);
        gload16(s0 + 1024 + L * 4, RsW + 1024);
    }
    FENCE();
    stage640(hw + (size_t)nwave * Hh, Rhw, L);
    FENCE();
    stage640(history + ((size_t)b0 * Nn + nwave) * Hh, Rb0, L);
    FENCE();
    float xAv[KB], xBv[KB];
    xAv[0] = x[(size_t)b0 * Nn + nA];
    xBv[0] = x[(size_t)b0 * Nn + nB];
    FENCE();

    asm volatile("s_waitcnt vmcnt(10)" ::: "memory");    // sW landed
    float wSA[10], wSB[10];
    #pragma unroll
    for (int i = 0; i < 10; ++i) {
        wSA[i] = RsW[10 * L + i];
        wSB[i] = RsW[640 + 10 * L + i];
    }
    LGKM0();                                             // sW reads done
    stage640(history + ((size_t)(b0 + 1) * Nn + nwave) * Hh, RsW, L);  // buf1
    xAv[1] = x[(size_t)(b0 + 1) * Nn + nA];
    xBv[1] = x[(size_t)(b0 + 1) * Nn + nB];
    FENCE();

    asm volatile("s_waitcnt vmcnt(12)" ::: "memory");    // hw landed
    float wAA[5], wAB[5];
    #pragma unroll
    for (int i = 0; i < 5; ++i) {
        wAA[i] = Rhw[5 * L + i];
        wAB[i] = Rhw[320 + 5 * L + i];
    }
    LGKM0();                                             // hw reads done
    stage640(history + ((size_t)(b0 + 2) * Nn + nwave) * Hh, Rhw, L);  // buf2
    xAv[2] = x[(size_t)(b0 + 2) * Nn + nA];
    xBv[2] = x[(size_t)(b0 + 2) * Nn + nB];
    FENCE();

    #pragma unroll
    for (int kb = 0; kb < KB; ++kb) {
        // wait: hist_kb landed (counts derived from the exact fenced issue order)
        if      (kb == 0) asm volatile("s_waitcnt vmcnt(14)" ::: "memory");
        else if (kb == 1) asm volatile("s_waitcnt vmcnt(16)" ::: "memory");
        else if (kb == 2) asm volatile("s_waitcnt vmcnt(18)" ::: "memory");
        else if (kb <= 5) asm volatile("s_waitcnt vmcnt(20)" ::: "memory");
        else if (kb == 6) asm volatile("s_waitcnt vmcnt(14)" ::: "memory");
        else              asm volatile("s_waitcnt vmcnt(8)"  ::: "memory");

        float* buf = (kb % 3 == 0) ? Rb0 : (kb % 3 == 1) ? RsW : Rhw;
        const int b = b0 + kb;

        float st[Ss];                        // uniform -> scalar loads (lgkm)
        #pragma unroll
        for (int i = 0; i < Ss; ++i) st[i] = state[(size_t)b * Ss + i];

        float hvA[5], hvB[5];
        #pragma unroll
        for (int i = 0; i < 5; ++i) {
            hvA[i] = buf[5 * L + i];
            hvB[i] = buf[320 + 5 * L + i];
        }

        float histA = hbA, histB = hbB;
        #pragma unroll
        for (int i = 0; i < 5; ++i) {
            histA = fmaf(hvA[i], wAA[i], histA);
            histB = fmaf(hvB[i], wAB[i], histB);
        }
        float smA = sbA, smB = sbB;
        #pragma unroll
        for (int i = 0; i < 10; ++i) {
            smA = fmaf(st[i], wSA[i], smA);
            smB = fmaf(st[i], wSB[i], smB);
        }
        float vA = xAv[kb] + histA + elu1(smA);
        float vB = xBv[kb] + histB + elu1(smB);
        float resA = fmaf(gaA, bg[kb], 1.0f) * (elu1(vA) + 1.0f);
        float resB = fmaf(gaB, bg[kb], 1.0f) * (elu1(vB) + 1.0f);

        LGKM0();    // all ds_reads of buf complete before its refill below
        if (kb + 3 < KB) {
            stage640(history + ((size_t)(b + 3) * Nn + nwave) * Hh, buf, L);
            xAv[kb + 3] = x[(size_t)(b + 3) * Nn + nA];
            xBv[kb + 3] = x[(size_t)(b + 3) * Nn + nB];
        }
        FENCE();
        out[(size_t)b * Nn + nA] = resA;
        out[(size_t)b * Nn + nB] = resB;
        FENCE();
    }
}

extern "C" void kernel_launch(void* const* d_in, const int* in_sizes, int n_in,
                              void* d_out, int out_size, void* d_ws, size_t ws_size,
                              hipStream_t stream) {
    const float* x        = (const float*)d_in[0];
    const float* history  = (const float*)d_in[1];
    // d_in[2] = gain (unused)
    const float* state    = (const float*)d_in[3];
    const int*   sort_id  = (const int*)d_in[4];
    const float* hw       = (const float*)d_in[5];
    const float* hb       = (const float*)d_in[6];
    const float* sW       = (const float*)d_in[7];
    const float* sb       = (const float*)d_in[8];
    const float* own_gain = (const float*)d_in[9];
    const float* ga       = (const float*)d_in[10];
    float* out = (float*)d_out;

    const int nblocks = TILES * (Bsz / KB);   // 16 * 64 = 1024 -> 4 blocks/CU
    main_kernel<<<nblocks, NT, 0, stream>>>(x, history, state, hw, hb, sW, sb,
                                            ga, sort_id, own_gain, out);
}

// Round 12
// 25.415 us; speedup vs baseline: 1.0702x; 1.0069x over previous
//
#include <hip/hip_runtime.h>
#include <stdint.h>

#define Bsz 512
#define Nn  8192
#define Hh  5
#define Ss  10
#define KB  8            // batches per block
#define TILE 512         // n per block
#define NT  256          // threads per block
#define TILES (Nn / TILE)   // 16

// Per-wave LDS region (floats): [0,1280) sW-stage (buf1 overlays [0,640))
//                               [1280,1920) hw-stage (= buf2 after prologue)
//                               [1920,2560) buf0
// buf(k) = k%3==0 ? buf0 : k%3==1 ? sW[0:640) : hw-region.  All wave-private.
#define WREG 2560
#define LDS_FLOATS (4 * WREG)   // 40 KB -> 4 blocks/CU exactly

#define FENCE() asm volatile("" ::: "memory")
#define LGKM0() asm volatile("s_waitcnt lgkmcnt(0)" ::: "memory")

__device__ __forceinline__ float elu1(float v) {
    return v > 0.0f ? v : __expf(v) - 1.0f;
}

__device__ __forceinline__ void gload16(const float* src, float* dst) {
    __builtin_amdgcn_global_load_lds(
        (const __attribute__((address_space(1))) uint32_t*)src,
        (__attribute__((address_space(3))) uint32_t*)dst, 16, 0, 0);
}
__device__ __forceinline__ void gload4(const float* src, float* dst) {
    __builtin_amdgcn_global_load_lds(
        (const __attribute__((address_space(1))) uint32_t*)src,
        (__attribute__((address_space(3))) uint32_t*)dst, 4, 0, 0);
}

// Stage 640 consecutive floats (2560 B) into a wave-private region: 2xg16 + 2xg4.
__device__ __forceinline__ void stage640(const float* src, float* dst, int L) {
    gload16(src + L * 4,       dst);
    gload16(src + 256 + L * 4, dst + 256);
    gload4 (src + 512 + L,     dst + 512);
    gload4 (src + 576 + L,     dst + 576);
}

__global__ __launch_bounds__(NT, 4) void main_kernel(
    const float* __restrict__ x,         // [B,N]
    const float* __restrict__ history,   // [B,N,H]
    const float* __restrict__ state,     // [B,S]
    const float* __restrict__ hw,        // [N,H]
    const float* __restrict__ hb,        // [N]
    const float* __restrict__ sW,        // [N,S]
    const float* __restrict__ sb,        // [N]
    const float* __restrict__ ga,        // [N]
    const int*   __restrict__ sort_id,   // [B]
    const float* __restrict__ own_gain,  // [T]
    float* __restrict__ out)             // [B,N]
{
    __shared__ __align__(16) float lds[LDS_FLOATS];

    const int tid = threadIdx.x;
    const int L   = tid & 63;
    const int w   = tid >> 6;
    const int tile  = blockIdx.x & (TILES - 1);
    const int chunk = blockIdx.x / TILES;
    const int n0 = tile * TILE;
    const int b0 = chunk * KB;
    // split-half ownership inside the wave's 128-n span -> 2-way-free LDS reads
    const int nA = n0 + 128 * w + L;
    const int nB = nA + 64;
    const int nwave = n0 + 128 * w;          // wave's first n

    float* WB  = &lds[w * WREG];
    float* RsW = WB;            // sW stage; [0,640) becomes buf1
    float* Rhw = WB + 1280;     // hw stage; becomes buf2
    float* Rb0 = WB + 1920;     // buf0

    // ---- gains (all vm loads here retire before the counted stream) ----
    float bg[KB];
    {
        int grp = L >> 3;                    // 8 groups x 8 lanes
        int r   = L & 7;
        int s   = sort_id[b0 + grp];
        int jmax = s < 100 ? s : 100;
        float acc = 0.0f;
        #pragma unroll
        for (int k = 0; k < 13; ++k) {
            int j = r + k * 8;
            if (j <= jmax) {
                float t = (float)j * (1.0f / 30.0f);
                acc = fmaf(__expf(-0.5f * t * t), own_gain[s - j], acc);
            }
        }
        acc += __shfl_xor(acc, 1);
        acc += __shfl_xor(acc, 2);
        acc += __shfl_xor(acc, 4);
        #pragma unroll
        for (int g = 0; g < KB; ++g)
            bg[g] = elu1(__shfl(acc, g * 8)) + 1.0f;
    }
    // biases (older than the counted stream -> drained first, counts stay valid)
    float hbA = hb[nA], hbB = hb[nB];
    float sbA = sb[nA], sbB = sb[nB];
    float gaA = ga[nA], gaB = ga[nB];
    FENCE();

    // ---- counted staging stream: [sW 5][hw 4][h0 4][x0 2] ----
    {
        const float* s0 = sW + (size_t)nwave * Ss;      // 1280 floats
        gload16(s0 + L * 4,        RsW);
        gload16(s0 + 256  + L * 4, RsW + 256);
        gload16(s0 + 512  + L * 4, RsW + 512);
        gload16(s0 + 768  + L * 4, RsW + 768);
        gload16(s0 + 1024 + L * 4, RsW + 1024);
    }
    FENCE();
    stage640(hw + (size_t)nwave * Hh, Rhw, L);
    FENCE();
    stage640(history + ((size_t)b0 * Nn + nwave) * Hh, Rb0, L);
    FENCE();
    float xAv[KB], xBv[KB];
    xAv[0] = x[(size_t)b0 * Nn + nA];
    xBv[0] = x[(size_t)b0 * Nn + nB];
    FENCE();

    asm volatile("s_waitcnt vmcnt(10)" ::: "memory");    // sW landed
    float wSA[10], wSB[10];
    #pragma unroll
    for (int i = 0; i < 10; ++i) {
        wSA[i] = RsW[10 * L + i];
        wSB[i] = RsW[640 + 10 * L + i];
    }
    LGKM0();                                             // sW reads done
    stage640(history + ((size_t)(b0 + 1) * Nn + nwave) * Hh, RsW, L);  // buf1
    xAv[1] = x[(size_t)(b0 + 1) * Nn + nA];
    xBv[1] = x[(size_t)(b0 + 1) * Nn + nB];
    FENCE();

    asm volatile("s_waitcnt vmcnt(12)" ::: "memory");    // hw landed
    float wAA[5], wAB[5];
    #pragma unroll
    for (int i = 0; i < 5; ++i) {
        wAA[i] = Rhw[5 * L + i];
        wAB[i] = Rhw[320 + 5 * L + i];
    }
    LGKM0();                                             // hw reads done
    stage640(history + ((size_t)(b0 + 2) * Nn + nwave) * Hh, Rhw, L);  // buf2
    xAv[2] = x[(size_t)(b0 + 2) * Nn + nA];
    xBv[2] = x[(size_t)(b0 + 2) * Nn + nB];
    FENCE();

    #pragma unroll
    for (int kb = 0; kb < KB; ++kb) {
        // wait: hist_kb landed (counts derived from the exact fenced issue order)
        if      (kb == 0) asm volatile("s_waitcnt vmcnt(14)" ::: "memory");
        else if (kb == 1) asm volatile("s_waitcnt vmcnt(16)" ::: "memory");
        else if (kb == 2) asm volatile("s_waitcnt vmcnt(18)" ::: "memory");
        else if (kb <= 5) asm volatile("s_waitcnt vmcnt(20)" ::: "memory");
        else if (kb == 6) asm volatile("s_waitcnt vmcnt(14)" ::: "memory");
        else              asm volatile("s_waitcnt vmcnt(8)"  ::: "memory");

        float* buf = (kb % 3 == 0) ? Rb0 : (kb % 3 == 1) ? RsW : Rhw;
        const int b = b0 + kb;

        float st[Ss];                        // uniform -> scalar loads (lgkm)
        #pragma unroll
        for (int i = 0; i < Ss; ++i) st[i] = state[(size_t)b * Ss + i];

        float hvA[5], hvB[5];
        #pragma unroll
        for (int i = 0; i < 5; ++i) {
            hvA[i] = buf[5 * L + i];
            hvB[i] = buf[320 + 5 * L + i];
        }

        float histA = hbA, histB = hbB;
        #pragma unroll
        for (int i = 0; i < 5; ++i) {
            histA = fmaf(hvA[i], wAA[i], histA);
            histB = fmaf(hvB[i], wAB[i], histB);
        }
        float smA = sbA, smB = sbB;
        #pragma unroll
        for (int i = 0; i < 10; ++i) {
            smA = fmaf(st[i], wSA[i], smA);
            smB = fmaf(st[i], wSB[i], smB);
        }
        float vA = xAv[kb] + histA + elu1(smA);
        float vB = xBv[kb] + histB + elu1(smB);
        float resA = fmaf(gaA, bg[kb], 1.0f) * (elu1(vA) + 1.0f);
        float resB = fmaf(gaB, bg[kb], 1.0f) * (elu1(vB) + 1.0f);

        LGKM0();    // all ds_reads of buf complete before its refill below
        if (kb + 3 < KB) {
            stage640(history + ((size_t)(b + 3) * Nn + nwave) * Hh, buf, L);
            xAv[kb + 3] = x[(size_t)(b + 3) * Nn + nA];
            xBv[kb + 3] = x[(size_t)(b + 3) * Nn + nB];
        }
        FENCE();
        __builtin_nontemporal_store(resA, out + (size_t)b * Nn + nA);
        __builtin_nontemporal_store(resB, out + (size_t)b * Nn + nB);
        FENCE();
    }
}

extern "C" void kernel_launch(void* const* d_in, const int* in_sizes, int n_in,
                              void* d_out, int out_size, void* d_ws, size_t ws_size,
                              hipStream_t stream) {
    const float* x        = (const float*)d_in[0];
    const float* history  = (const float*)d_in[1];
    // d_in[2] = gain (unused)
    const float* state    = (const float*)d_in[3];
    const int*   sort_id  = (const int*)d_in[4];
    const float* hw       = (const float*)d_in[5];
    const float* hb       = (const float*)d_in[6];
    const float* sW       = (const float*)d_in[7];
    const float* sb       = (const float*)d_in[8];
    const float* own_gain = (const float*)d_in[9];
    const float* ga       = (const float*)d_in[10];
    float* out = (float*)d_out;

    const int nblocks = TILES * (Bsz / KB);   // 16 * 64 = 1024 -> 4 blocks/CU
    main_kernel<<<nblocks, NT, 0, stream>>>(x, history, state, hw, hb, sW, sb,
                                            ga, sort_id, own_gain, out);
}